// Round 17
// baseline (214.249 us; speedup 1.0000x reference)
//
#include <hip/hip_runtime.h>
#include <hip/hip_bf16.h>

// Problem constants
#define BATCH 2
#define SEQ 512
#define DIM 768
#define HEADS 12
#define NEXP 8
#define FFDIM 3072
#define HDIM 64
#define NTOK (BATCH*SEQ)          // 1024
#define NENT (2*NTOK)             // 2048 (token, slot) entries
#define YPS ((long)NENT * DIM)    // partial-buffer stride

typedef __hip_bfloat16 bf16;
typedef __attribute__((ext_vector_type(8))) short s8v;
typedef __attribute__((ext_vector_type(4))) float f4v;

// ---- async global->LDS (16B per lane, wave-uniform LDS base + lane*16) ----
typedef __attribute__((address_space(1))) const unsigned char gas_u8;
typedef __attribute__((address_space(3))) unsigned char las_u8;
__device__ __forceinline__ void gload16(const void* g, void* l) {
    __builtin_amdgcn_global_load_lds((gas_u8*)g, (las_u8*)l, 16, 0, 0);
}

__device__ __forceinline__ float bfbits2f(unsigned hi16) {
    union { unsigned u; float f; } c; c.u = hi16; return c.f;
}
__device__ __forceinline__ unsigned short bf16bits(float f) {
    bf16 h = __float2bfloat16(f);
    return *reinterpret_cast<unsigned short*>(&h);
}

// ---------------- LayerNorm (LN1): one block per token ----------------
__global__ __launch_bounds__(256) void ln_kernel(const float* __restrict__ x,
                                                 const float* __restrict__ g,
                                                 const float* __restrict__ b,
                                                 bf16* __restrict__ outb) {
    int t = blockIdx.x;
    const float* xr = x + (long)t * DIM;
    int tid = threadIdx.x;
    float v0 = xr[tid], v1 = xr[tid + 256], v2 = xr[tid + 512];
    float s = v0 + v1 + v2;
    __shared__ float red[4];
    #pragma unroll
    for (int o = 32; o; o >>= 1) s += __shfl_xor(s, o);
    if ((tid & 63) == 0) red[tid >> 6] = s;
    __syncthreads();
    s = red[0] + red[1] + red[2] + red[3];
    float mu = s * (1.f / DIM);
    float d0 = v0 - mu, d1 = v1 - mu, d2 = v2 - mu;
    float q = d0*d0 + d1*d1 + d2*d2;
    __shared__ float red2[4];
    #pragma unroll
    for (int o = 32; o; o >>= 1) q += __shfl_xor(q, o);
    if ((tid & 63) == 0) red2[tid >> 6] = q;
    __syncthreads();
    q = red2[0] + red2[1] + red2[2] + red2[3];
    float rstd = rsqrtf(q * (1.f / DIM) + 1e-5f);
    bf16* ob = outb + (long)t * DIM;
    ob[tid]       = __float2bfloat16(d0 * rstd * g[tid]       + b[tid]);
    ob[tid + 256] = __float2bfloat16(d1 * rstd * g[tid + 256] + b[tid + 256]);
    ob[tid + 512] = __float2bfloat16(d2 * rstd * g[tid + 512] + b[tid + 512]);
}

// ---------------- LN2 fused with x1 assembly ----------------
// x1 = x + out_b + opart0 + opart1 ; t2/t2b = LN(x1)
__global__ __launch_bounds__(256) void ln2x1_kernel(const float* __restrict__ x,
                                                    const float* __restrict__ out_b,
                                                    const float* __restrict__ op,
                                                    const float* __restrict__ g,
                                                    const float* __restrict__ b,
                                                    float* __restrict__ x1,
                                                    float* __restrict__ t2,
                                                    bf16* __restrict__ t2b) {
    int t = blockIdx.x;
    long base = (long)t * DIM;
    int tid = threadIdx.x;
    const long TDl = (long)NTOK * DIM;
    float v[3];
    #pragma unroll
    for (int i = 0; i < 3; ++i) {
        long idx = base + tid + i * 256;
        v[i] = x[idx] + out_b[tid + i * 256] + op[idx] + op[idx + TDl];
        x1[idx] = v[i];
    }
    float s = v[0] + v[1] + v[2];
    __shared__ float red[4];
    #pragma unroll
    for (int o = 32; o; o >>= 1) s += __shfl_xor(s, o);
    if ((tid & 63) == 0) red[tid >> 6] = s;
    __syncthreads();
    s = red[0] + red[1] + red[2] + red[3];
    float mu = s * (1.f / DIM);
    float d[3];
    float q = 0.f;
    #pragma unroll
    for (int i = 0; i < 3; ++i) { d[i] = v[i] - mu; q += d[i] * d[i]; }
    __shared__ float red2[4];
    #pragma unroll
    for (int o = 32; o; o >>= 1) q += __shfl_xor(q, o);
    if ((tid & 63) == 0) red2[tid >> 6] = q;
    __syncthreads();
    q = red2[0] + red2[1] + red2[2] + red2[3];
    float rstd = rsqrtf(q * (1.f / DIM) + 1e-5f);
    #pragma unroll
    for (int i = 0; i < 3; ++i) {
        long idx = base + tid + i * 256;
        float o = d[i] * rstd * g[tid + i * 256] + b[tid + i * 256];
        t2[idx] = o;
        t2b[idx] = __float2bfloat16(o);
    }
}

// ---------------- MFMA GEMM, parameterized tile (attention-side) ----------------
// C[m,n] = alpha * sum_k A[m,k] * B[n,k]   (A,B bf16 row-major [.][K])
// Tile BM=32*WM x BN=32*WN, 4 waves in 2x2 grid.
// OUTMODE: 0 = f32 store, 1 = bf16 store, 2 = f32 atomicAdd.
template<int WM, int WN, bool GROUPED, bool GELU, int OUTMODE>
__global__ __launch_bounds__(256) void mfma_gemm(
    const bf16* __restrict__ A, const bf16* __restrict__ B,
    const float* __restrict__ bias, const float* __restrict__ resid,
    void* __restrict__ Cv,
    int M, int N, int K, int lda, int ldb, int ldc,
    int zdiv, int ksplit,
    long a_hi, long a_lo, long b_hi, long b_lo, long c_hi, long c_lo,
    long bias_stride, const int* __restrict__ grp_off, float alpha)
{
    constexpr int BM = 32 * WM, BN = 32 * WN;
    constexpr int ACH = BM * 4;     // 16B chunks in A tile
    constexpr int BCH = BN * 4;

    int z = blockIdx.z;
    int ze = z / ksplit, ks = z % ksplit;
    int kper = K / ksplit;
    long aoff, boff, coff;
    int m_count = M;
    if (GROUPED) {
        int m0 = grp_off[ze], m1 = grp_off[ze + 1];
        m_count = m1 - m0;
        if ((int)blockIdx.y * BM >= m_count) return;
        aoff = (long)m0 * lda;
        coff = (long)m0 * ldc;
        boff = (long)ze * b_hi;
    } else {
        int zh = ze / zdiv, zl = ze % zdiv;
        aoff = zh * a_hi + zl * a_lo;
        boff = zh * b_hi + zl * b_lo;
        coff = zh * c_hi + zl * c_lo;
    }
    const short* Ag = (const short*)(A + aoff);
    const short* Bg = (const short*)(B + boff);
    const float* biasp = bias ? bias + (long)ze * bias_stride : nullptr;
    float* Cf = (float*)Cv + coff;
    bf16*  Cb = (bf16*)Cv + coff;

    __shared__ short As[BM * 32];
    __shared__ short Bs[BN * 32];

    int tid = threadIdx.x;
    int wv = tid >> 6, ln = tid & 63;
    int wr = wv >> 1, wc = wv & 1;
    int fr = ln & 15, fq = ln >> 4;
    int bm = blockIdx.y * BM, bn = blockIdx.x * BN;

    f4v acc[WM][WN] = {};

    for (int k0 = ks * kper; k0 < (ks + 1) * kper; k0 += 32) {
        #pragma unroll
        for (int is = 0; is < ACH / 256; ++is) {
            int c = is * 256 + wv * 64 + ln;
            int m = c >> 2, kq = c & 3;
            gload16(Ag + (long)(bm + m) * lda + k0 + kq * 8,
                    &As[(is * 256 + wv * 64) * 8]);
        }
        if constexpr (ACH % 256) {
            if (tid < ACH % 256) {
                int c = (ACH / 256) * 256 + tid;
                int m = c >> 2, kq = c & 3;
                gload16(Ag + (long)(bm + m) * lda + k0 + kq * 8,
                        &As[((ACH / 256) * 256 + wv * 64) * 8]);
            }
        }
        #pragma unroll
        for (int is = 0; is < BCH / 256; ++is) {
            int c = is * 256 + wv * 64 + ln;
            int m = c >> 2, kq = c & 3;
            gload16(Bg + (long)(bn + m) * ldb + k0 + kq * 8,
                    &Bs[(is * 256 + wv * 64) * 8]);
        }
        if constexpr (BCH % 256) {
            if (tid < BCH % 256) {
                int c = (BCH / 256) * 256 + tid;
                int m = c >> 2, kq = c & 3;
                gload16(Bg + (long)(bn + m) * ldb + k0 + kq * 8,
                        &Bs[((BCH / 256) * 256 + wv * 64) * 8]);
            }
        }
        __syncthreads();
        s8v av[WM], bv[WN];
        #pragma unroll
        for (int i = 0; i < WM; ++i)
            av[i] = *(const s8v*)&As[(wr * (WM * 16) + i * 16 + fr) * 32 + fq * 8];
        #pragma unroll
        for (int j = 0; j < WN; ++j)
            bv[j] = *(const s8v*)&Bs[(wc * (WN * 16) + j * 16 + fr) * 32 + fq * 8];
        #pragma unroll
        for (int i = 0; i < WM; ++i)
            #pragma unroll
            for (int j = 0; j < WN; ++j)
                acc[i][j] = __builtin_amdgcn_mfma_f32_16x16x32_bf16(av[i], bv[j], acc[i][j], 0, 0, 0);
        __syncthreads();
    }

    #pragma unroll
    for (int i = 0; i < WM; ++i) {
        #pragma unroll
        for (int r = 0; r < 4; ++r) {
            int row = bm + wr * (WM * 16) + i * 16 + fq * 4 + r;
            if (GROUPED && row >= m_count) continue;
            #pragma unroll
            for (int j = 0; j < WN; ++j) {
                int col = bn + wc * (WN * 16) + j * 16 + fr;
                if (col < N) {
                    float v = acc[i][j][r] * alpha;
                    if (OUTMODE == 2) {
                        atomicAdd(&Cf[(long)row * ldc + col], v);
                    } else {
                        if (biasp) v += biasp[col];
                        if (GELU) v = 0.5f * v * (1.f + erff(v * 0.70710678118654752f));
                        if (resid) v += resid[(long)row * ldc + col];
                        if (OUTMODE == 1) Cb[(long)row * ldc + col] = __float2bfloat16(v);
                        else              Cf[(long)row * ldc + col] = v;
                    }
                }
            }
        }
    }
}

// ---------------- MoE grouped GEMM v11: gather-fused A, split-K partial stores
// BM=FM*32, BN=FN*32 (2x2 wave grid), BK=32, 3 LDS buffers, counted vmcnt(G).
// GATHER: A row for block-row m is entry_tok[m0+bm+m] (indices preloaded into
// registers — fixed per (thread, chunk)); else A rows contiguous from m0.
// B bf16 [e][N][ldb]; staged via gload_lds with global-side XOR swizzle.
// OUTMODE: 0 = f32 store at ks*pstride (split-K partials); 1 = bf16 store
// (+bias,+GELU) — requires KS==1.
template<int FM, int FN, int XT, int YCAP, int KS, bool GELU, int OUTMODE, bool GATHER>
__global__ __launch_bounds__(256) void moe_gemm(
    const bf16* __restrict__ A, const bf16* __restrict__ B,
    const float* __restrict__ bias, void* __restrict__ Cv,
    int lda, int ldb, int ldc, int Ktot, long b_hi, long bias_stride,
    const int* __restrict__ grp_off, const int* __restrict__ entry_tok,
    int N, long pstride)
{
    static_assert(OUTMODE != 1 || KS == 1, "plain bf16 store requires no split-K");
    constexpr int BM = FM * 32, BN = FN * 32;
    constexpr int GA = BM / 64;          // A gload16 per wave per tile
    constexpr int GB = BN / 64;          // B gload16 per wave per tile
    constexpr int G = GA + GB;

    int bid = blockIdx.x;
    int e = bid & 7;
    int r = bid >> 3;
    int xt = r % XT; r /= XT;
    int yt = r % YCAP;
    int ks = r / YCAP;
    int m0 = grp_off[e], m1 = grp_off[e + 1];
    int m_count = m1 - m0;
    int bm = yt * BM;
    if (bm >= m_count) return;
    int bn = xt * BN;
    int kper = Ktot / KS;                // multiple of 32

    const short* Ag = (const short*)A + (GATHER ? 0 : (long)m0 * lda);
    const short* Bg = (const short*)(B + (long)e * b_hi);
    const float* biasp = bias ? bias + (long)e * bias_stride : nullptr;
    float* Cf = (float*)Cv + (long)m0 * ldc + (long)ks * pstride;
    bf16*  Cb = (bf16*)Cv + (long)m0 * ldc;

    __shared__ short As[3][BM * 32];     // [m][k] rows of 64B
    __shared__ short Bs[3][BN * 32];     // [n][k]

    int tid = threadIdx.x;
    int wv = tid >> 6, ln = tid & 63;
    int wr = wv >> 1, wc = wv & 1;       // 2x2 wave grid
    int fr = ln & 15, fq = ln >> 4;      // fq in 0..3 = 16B k-chunk

    // Per-thread A row bases (fixed across K iterations).
    long arow[GA];
    #pragma unroll
    for (int is = 0; is < GA; ++is) {
        int c = is * 256 + wv * 64 + ln;
        int m = c >> 2;
        if (GATHER) {
            int gi = m0 + bm + m;
            arow[is] = (long)entry_tok[gi < NENT ? gi : NENT - 1] * lda;
        } else {
            arow[is] = (long)(bm + m) * lda;
        }
    }

    f4v acc[FM][FN] = {};

    auto stage = [&](int buf, int k0) {
        #pragma unroll
        for (int is = 0; is < GA; ++is) {
            int c = is * 256 + wv * 64 + ln;       // A chunks
            int m = c >> 2, q = c & 3;
            int qg = q ^ ((m >> 1) & 3);
            gload16(Ag + arow[is] + k0 + qg * 8,
                    &As[buf][(is * 256 + wv * 64) * 8]);
        }
        #pragma unroll
        for (int is = 0; is < GB; ++is) {
            int c = is * 256 + wv * 64 + ln;       // B chunks
            int n = c >> 2, q = c & 3;
            int qg = q ^ ((n >> 1) & 3);
            gload16(Bg + (long)(bn + n) * ldb + k0 + qg * 8,
                    &Bs[buf][(is * 256 + wv * 64) * 8]);
        }
    };

    int kbeg = ks * kper;
    int nit = kper / 32;
    stage(0, kbeg);
    if (nit > 1) stage(1, kbeg + 32);

    for (int it = 0; it < nit; ++it) {
        if (it + 1 < nit) asm volatile("s_waitcnt vmcnt(%0)" :: "i"(G) : "memory");
        else              asm volatile("s_waitcnt vmcnt(0)" ::: "memory");
        __builtin_amdgcn_s_barrier();
        if (it + 2 < nit) stage((it + 2) % 3, kbeg + (it + 2) * 32);
        int cur = it % 3;
        __builtin_amdgcn_s_setprio(1);
        {
            s8v av[FM], bv[FN];
            #pragma unroll
            for (int i = 0; i < FM; ++i) {
                int row = wr * (FM * 16) + i * 16 + fr;
                av[i] = *(const s8v*)&As[cur][row * 32 + (fq ^ ((row >> 1) & 3)) * 8];
            }
            #pragma unroll
            for (int j = 0; j < FN; ++j) {
                int row = wc * (FN * 16) + j * 16 + fr;
                bv[j] = *(const s8v*)&Bs[cur][row * 32 + (fq ^ ((row >> 1) & 3)) * 8];
            }
            #pragma unroll
            for (int i = 0; i < FM; ++i)
                #pragma unroll
                for (int j = 0; j < FN; ++j)
                    acc[i][j] = __builtin_amdgcn_mfma_f32_16x16x32_bf16(av[i], bv[j], acc[i][j], 0, 0, 0);
        }
        __builtin_amdgcn_s_setprio(0);
    }

    #pragma unroll
    for (int i = 0; i < FM; ++i) {
        #pragma unroll
        for (int rr = 0; rr < 4; ++rr) {
            int row = bm + wr * (FM * 16) + i * 16 + fq * 4 + rr;
            if (row >= m_count) continue;
            #pragma unroll
            for (int j = 0; j < FN; ++j) {
                int col = bn + wc * (FN * 16) + j * 16 + fr;
                float v = acc[i][j][rr];
                if (OUTMODE == 0) {
                    Cf[(long)row * ldc + col] = v;          // split-K partial
                } else {
                    if (biasp) v += biasp[col];
                    if (GELU) v = 0.5f * v * (1.f + erff(v * 0.70710678118654752f));
                    Cb[(long)row * ldc + col] = __float2bfloat16(v);
                }
            }
        }
    }
}

// ---------------- softmax over 512, bf16 in -> bf16 out, wave per row --------
__global__ __launch_bounds__(256) void softmax512b(const bf16* __restrict__ s,
                                                   bf16* __restrict__ attn) {
    long row = (long)blockIdx.x * 4 + (threadIdx.x >> 6);
    int ln = threadIdx.x & 63;
    const unsigned* p = (const unsigned*)(s + row * 512);
    uint4 v = *(const uint4*)(p + ln * 4);
    unsigned u[4] = {v.x, v.y, v.z, v.w};
    float f[8];
    #pragma unroll
    for (int j = 0; j < 4; ++j) {
        f[2*j]   = bfbits2f(u[j] << 16);
        f[2*j+1] = bfbits2f(u[j] & 0xffff0000u);
    }
    float m = f[0];
    #pragma unroll
    for (int j = 1; j < 8; ++j) m = fmaxf(m, f[j]);
    #pragma unroll
    for (int o = 32; o; o >>= 1) m = fmaxf(m, __shfl_xor(m, o));
    float e[8], ssum = 0.f;
    #pragma unroll
    for (int j = 0; j < 8; ++j) { e[j] = expf(f[j] - m); ssum += e[j]; }
    #pragma unroll
    for (int o = 32; o; o >>= 1) ssum += __shfl_xor(ssum, o);
    float inv = 1.f / ssum;
    unsigned w[4];
    #pragma unroll
    for (int j = 0; j < 4; ++j) {
        bf16 lo = __float2bfloat16(e[2*j] * inv);
        bf16 hi = __float2bfloat16(e[2*j+1] * inv);
        w[j] = ((unsigned)*(unsigned short*)&hi << 16) | *(unsigned short*)&lo;
    }
    uint4 o4; o4.x = w[0]; o4.y = w[1]; o4.z = w[2]; o4.w = w[3];
    *(uint4*)((unsigned*)(attn + row * 512) + ln * 4) = o4;
}

// ---------------- V transpose: qkv bf16 [tok][2304] -> vt [z][64][512] ------
__global__ __launch_bounds__(256) void vt_kernel(const bf16* __restrict__ qkvb,
                                                 bf16* __restrict__ vt) {
    int st = blockIdx.x;
    int z = blockIdx.y;
    int b = z / HEADS, h = z % HEADS;
    __shared__ short tile[64][65];
    int t = threadIdx.x;
    int d = t & 63, s0 = t >> 6;
    const short* q = (const short*)qkvb;
    #pragma unroll
    for (int i = 0; i < 16; ++i) {
        int s = st * 64 + s0 + i * 4;
        tile[s0 + i * 4][d] = q[(long)(b * SEQ + s) * 2304 + 2 * DIM + h * HDIM + d];
    }
    __syncthreads();
    short* o = (short*)vt;
    #pragma unroll
    for (int i = 0; i < 16; ++i) {
        int d2 = (t >> 6) + i * 4;
        o[(long)(z * 64 + d2) * 512 + st * 64 + (t & 63)] = tile[t & 63][d2];
    }
}

// ---------------- merged weight transpose-convert (w1 + w2), VECTORIZED -----
// w1: f32 [8][768][3072] -> bf16 [8][3072][768]; w2: f32 [8][3072][768] -> ...
// Loads float4/thread (256B/row segments), stores uint2 (4 bf16, 8B).
__global__ __launch_bounds__(256) void wtrans2_kernel(const float* __restrict__ w1,
                                                      bf16* __restrict__ w1t,
                                                      const float* __restrict__ w2,
                                                      bf16* __restrict__ w2t) {
    int id = blockIdx.x;                 // 0..9215
    const float* in; bf16* out; int R, C, e, ct, rt;
    if (id < 4608) {                     // w1: 8 x (48 ct x 12 rt)
        e = id / 576; int rem = id % 576; ct = rem / 12; rt = rem % 12;
        in = w1; out = w1t; R = DIM; C = FFDIM;
    } else {                             // w2: 8 x (12 ct x 48 rt)
        id -= 4608;
        e = id / 576; int rem = id % 576; ct = rem / 48; rt = rem % 48;
        in = w2; out = w2t; R = FFDIM; C = DIM;
    }
    long ibase = (long)e * R * C;
    int rt0 = rt * 64, ct0 = ct * 64;
    __shared__ float tile[64][68];       // pad 68: 16B-aligned rows, writes 2-way
    int t = threadIdx.x;
    {
        int r = t >> 4;                  // 0..15
        int cq = t & 15;                 // col quad
        #pragma unroll
        for (int i = 0; i < 4; ++i) {
            int row = r + i * 16;
            float4 v = *(const float4*)&in[ibase + (long)(rt0 + row) * C + ct0 + cq * 4];
            *(float4*)&tile[row][cq * 4] = v;
        }
    }
    __syncthreads();
    {
        int q = t >> 6;                  // 0..3
        int cc = t & 63;                 // output row within tile
        #pragma unroll
        for (int i = 0; i < 4; ++i) {
            int rr0 = i * 16 + q * 4;
            unsigned lo = ((unsigned)bf16bits(tile[rr0 + 1][cc]) << 16) | bf16bits(tile[rr0][cc]);
            unsigned hi = ((unsigned)bf16bits(tile[rr0 + 3][cc]) << 16) | bf16bits(tile[rr0 + 2][cc]);
            uint2 u; u.x = lo; u.y = hi;
            *(uint2*)&out[ibase + (long)(ct0 + cc) * R + rt0 + rr0] = u;
        }
    }
}

// ---------------- dual f32 -> bf16 convert (merged launches) ----------------
__global__ __launch_bounds__(256) void cvt2_kernel(const float* __restrict__ a, long na,
                                                   const float* __restrict__ b, long nb,
                                                   bf16* __restrict__ oa,
                                                   bf16* __restrict__ ob) {
    long i = ((long)blockIdx.x * 256 + threadIdx.x) * 4;
    const float* src; bf16* dst; long idx;
    if (i < na) { src = a; dst = oa; idx = i; }
    else if (i < na + nb) { src = b; dst = ob; idx = i - na; }
    else return;
    float4 v = *(const float4*)(src + idx);
    dst[idx]     = __float2bfloat16(v.x);
    dst[idx + 1] = __float2bfloat16(v.y);
    dst[idx + 2] = __float2bfloat16(v.z);
    dst[idx + 3] = __float2bfloat16(v.w);
}

// ---------------- router: logits, softmax, top2, renorm ----------------
__global__ __launch_bounds__(64) void router_kernel(const float* __restrict__ t2,
                                                    const float* __restrict__ rw,
                                                    const float* __restrict__ rb,
                                                    int* __restrict__ e_sel,
                                                    float* __restrict__ w_sel) {
    int t = blockIdx.x;
    int lane = threadIdx.x;
    const float* tr = t2 + (long)t * DIM;
    float tv[12];
    #pragma unroll
    for (int i = 0; i < 12; ++i) tv[i] = tr[lane + 64 * i];
    float logits[NEXP];
    #pragma unroll
    for (int e = 0; e < NEXP; ++e) {
        const float* wr = rw + (long)e * DIM;
        float s = 0.f;
        #pragma unroll
        for (int i = 0; i < 12; ++i) s += tv[i] * wr[lane + 64 * i];
        #pragma unroll
        for (int o = 32; o; o >>= 1) s += __shfl_xor(s, o);
        logits[e] = s + rb[e];
    }
    if (lane == 0) {
        int e0 = -1, e1 = -1;
        float l0 = -1e30f, l1 = -1e30f;
        #pragma unroll
        for (int e = 0; e < NEXP; ++e) {
            float l = logits[e];
            if (l > l0) { l1 = l0; e1 = e0; l0 = l; e0 = e; }
            else if (l > l1) { l1 = l; e1 = e; }
        }
        float p1 = expf(l1 - l0);
        float inv = 1.f / (1.f + p1);
        e_sel[t * 2] = e0;  e_sel[t * 2 + 1] = e1;
        w_sel[t * 2] = inv; w_sel[t * 2 + 1] = p1 * inv;
    }
}

// ---------------- build per-expert entry lists (single block) ----------------
__global__ __launch_bounds__(1024) void build_lists(const int* __restrict__ e_sel,
                                                    int* __restrict__ entry_tok,
                                                    int* __restrict__ pos,
                                                    int* __restrict__ grp_off) {
    __shared__ int cnt[NEXP];
    __shared__ int off[NEXP + 1];
    __shared__ int cur[NEXP];
    int tid = threadIdx.x;
    if (tid < NEXP) cnt[tid] = 0;
    __syncthreads();
    for (int i = tid; i < NENT; i += 1024) atomicAdd(&cnt[e_sel[i]], 1);
    __syncthreads();
    if (tid == 0) {
        off[0] = 0;
        for (int e = 0; e < NEXP; ++e) off[e + 1] = off[e] + cnt[e];
        for (int e = 0; e < NEXP; ++e) cur[e] = off[e];
    }
    __syncthreads();
    for (int i = tid; i < NENT; i += 1024) {
        int e = e_sel[i];
        int p = atomicAdd(&cur[e], 1);
        entry_tok[p] = i >> 1;
        pos[i] = p;
    }
    if (tid < NEXP + 1) grp_off[tid] = off[tid];
}

// ---------------- final combine: out = x1 + sum_s w_s*(b2[e_s] + sum_ks part) -
__global__ __launch_bounds__(256) void combine_kernel(const float* __restrict__ x1,
                                                      const float* __restrict__ ypart,
                                                      const float* __restrict__ b2,
                                                      const int* __restrict__ pos,
                                                      const int* __restrict__ e_sel,
                                                      const float* __restrict__ wsel,
                                                      float* __restrict__ out) {
    long i = (long)blockIdx.x * 256 + threadIdx.x;
    if (i >= (long)NTOK * DIM) return;
    int t = (int)(i / DIM), d = (int)(i % DIM);
    float v = x1[i];
    #pragma unroll
    for (int s = 0; s < 2; ++s) {
        long base = (long)pos[t * 2 + s] * DIM + d;
        float y = b2[(long)e_sel[t * 2 + s] * DIM + d];
        #pragma unroll
        for (int ks = 0; ks < 4; ++ks) y += ypart[base + ks * YPS];
        v += wsel[t * 2 + s] * y;
    }
    out[i] = v;
}

extern "C" void kernel_launch(void* const* d_in, const int* in_sizes, int n_in,
                              void* d_out, int out_size, void* d_ws, size_t ws_size,
                              hipStream_t stream) {
    const float* x        = (const float*)d_in[0];
    const float* ln1_g    = (const float*)d_in[1];
    const float* ln1_b    = (const float*)d_in[2];
    const float* ln2_g    = (const float*)d_in[3];
    const float* ln2_b    = (const float*)d_in[4];
    const float* in_w     = (const float*)d_in[5];
    const float* in_b     = (const float*)d_in[6];
    const float* out_w    = (const float*)d_in[7];
    const float* out_b    = (const float*)d_in[8];
    const float* router_w = (const float*)d_in[9];
    const float* router_b = (const float*)d_in[10];
    const float* w1       = (const float*)d_in[11];
    const float* b1       = (const float*)d_in[12];
    const float* w2       = (const float*)d_in[13];
    const float* b2       = (const float*)d_in[14];
    float* out = (float*)d_out;

    const long TD = (long)NTOK * DIM;
    char* p = (char*)d_ws;
    size_t off = 0;
    auto alloc = [&](size_t bytes) -> void* {
        void* r = p + off; off += (bytes + 255) & ~(size_t)255; return r;
    };
    bf16*  h_b    = (bf16*)alloc(TD * 2);
    bf16*  in_wb  = (bf16*)alloc(2304L * 768 * 2);
    bf16*  qkv_b  = (bf16*)alloc(1024L * 2304 * 2);
    bf16*  out_wb = (bf16*)alloc(768L * 768 * 2);
    bf16*  vt_b   = (bf16*)alloc((24L * 64 + 64) * 512 * 2);
    bf16*  oat_b  = (bf16*)alloc(TD * 2);
    float* opart  = (float*)alloc(2 * TD * 4);                 // out-proj K-partials
    float* x1     = (float*)alloc(TD * 4);
    float* t2     = (float*)alloc(TD * 4);
    bf16*  t2b    = (bf16*)alloc((NTOK + 256L) * DIM * 2);     // +pad (BM overread)
    bf16*  w1t    = (bf16*)alloc(8L * 3072 * 768 * 2);         // aliased: scores+attn bf16
    bf16*  w2t    = (bf16*)alloc(8L * 768 * 3072 * 2);
    bf16*  hid    = (bf16*)alloc((2048L + 256) * 3072 * 2);    // +pad
    float* ypart  = (float*)alloc(4 * YPS * 4);                // 4 split-K partials
    int*   e_sel     = (int*)alloc(NENT * 4);
    float* w_sel     = (float*)alloc(NENT * 4);
    int*   entry_tok = (int*)alloc(NENT * 4);
    int*   pos       = (int*)alloc(NENT * 4);
    int*   grp_off   = (int*)alloc(64);
    // scores/attn (bf16, 12.58 MB each) alias the not-yet-written w1t region;
    // wtrans2 runs only after PV has consumed attn.
    bf16* scores = w1t;
    bf16* attn   = (bf16*)((char*)w1t + 24L * 512 * 512 * 2);

    // 1. LN1 -> h bf16
    ln_kernel<<<NTOK, 256, 0, stream>>>(x, ln1_g, ln1_b, h_b);
    // 2. attention weight converts (merged; already [N][K])
    cvt2_kernel<<<2304, 256, 0, stream>>>(in_w, 2304L * 768, out_w, 768L * 768,
                                          in_wb, out_wb);
    // 3. qkv = h @ in_w^T + in_b -> bf16 [1024,2304]   BN=64: 576 blocks
    mfma_gemm<2, 2, false, false, 1><<<dim3(36, 16, 1), 256, 0, stream>>>(
        h_b, in_wb, in_b, nullptr, qkv_b,
        NTOK, 3 * DIM, DIM, DIM, DIM, 3 * DIM,
        1, 1, 0, 0, 0, 0, 0, 0, 0, nullptr, 1.f);
    // 4. scores = Q @ K^T / 8 -> bf16 [24][512][512]   768 blocks
    mfma_gemm<2, 4, false, false, 1><<<dim3(4, 8, 24), 256, 0, stream>>>(
        qkv_b, qkv_b + DIM, nullptr, nullptr, scores,
        SEQ, SEQ, HDIM, 3 * DIM, 3 * DIM, SEQ,
        HEADS, 1, (long)SEQ * 3 * DIM, HDIM, (long)SEQ * 3 * DIM, HDIM,
        (long)HEADS * SEQ * SEQ, (long)SEQ * SEQ,
        0, nullptr, 0.125f);
    // 5. softmax (wave per row) -> attn bf16
    softmax512b<<<24 * SEQ / 4, 256, 0, stream>>>(scores, attn);
    // 6. V transpose
    vt_kernel<<<dim3(8, 24), 256, 0, stream>>>(qkv_b, vt_b);
    // 7. o = attn @ V -> oat bf16   BM=32: 384 blocks
    mfma_gemm<1, 2, false, false, 1><<<dim3(1, 16, 24), 256, 0, stream>>>(
        attn, vt_b, nullptr, nullptr, oat_b,
        SEQ, HDIM, SEQ, SEQ, SEQ, DIM,
        HEADS, 1, (long)HEADS * SEQ * SEQ, (long)SEQ * SEQ,
        (long)HEADS * HDIM * SEQ, (long)HDIM * SEQ,
        (long)SEQ * DIM, HDIM,
        0, nullptr, 1.f);
    // 8. out-proj split-K x2, plain partial stores (no atomics, no prefill):
    //    opart[z] = oat[:, z*384:] @ out_w[:, z*384:]^T
    mfma_gemm<2, 2, false, false, 0><<<dim3(12, 16, 2), 256, 0, stream>>>(
        oat_b, out_wb, nullptr, nullptr, opart,
        NTOK, DIM, 384, DIM, DIM, DIM,
        2, 1, 0, 384, 0, 384, 0, TD, 0, nullptr, 1.f);
    // 9. LN2 fused with x1 assembly: x1 = x + out_b + opart0 + opart1; LN -> t2,t2b
    ln2x1_kernel<<<NTOK, 256, 0, stream>>>(x, out_b, opart, ln2_g, ln2_b,
                                           x1, t2, t2b);
    // 10. router
    router_kernel<<<NTOK, 64, 0, stream>>>(t2, router_w, router_b, e_sel, w_sel);
    // 11. build lists
    build_lists<<<1, 1024, 0, stream>>>(e_sel, entry_tok, pos, grp_off);
    // 12. merged weight transpose-convert, vectorized (after PV consumed attn)
    wtrans2_kernel<<<9216, 256, 0, stream>>>(w1, w1t, w2, w2t);
    // 13. FFN1 grouped, GATHER-fused A: hid = gelu(t2b[tok] @ w1t^T + b1) -> bf16
    moe_gemm<4, 4, 24, 8, 1, true, 1, true><<<8 * 24 * 8, 256, 0, stream>>>(
        t2b, w1t, b1, hid,
        DIM, DIM, FFDIM, DIM, (long)FFDIM * DIM, FFDIM, grp_off, entry_tok,
        FFDIM, 0);
    // 14. FFN2 grouped split-K x4, plain partial stores
    moe_gemm<4, 4, 6, 8, 4, false, 0, false><<<8 * 6 * 8 * 4, 256, 0, stream>>>(
        hid, w2t, nullptr, ypart,
        FFDIM, FFDIM, DIM, FFDIM, (long)DIM * FFDIM, 0, grp_off, nullptr,
        DIM, YPS);
    // 15. combine: out = x1 + sum_s w_s*(b2[e_s] + sum_ks ypart)
    combine_kernel<<<3072, 256, 0, stream>>>(x1, ypart, b2, pos, e_sel, w_sel, out);
}

// Round 18
// 184.950 us; speedup vs baseline: 1.1584x; 1.1584x over previous
//
#include <hip/hip_runtime.h>
#include <hip/hip_bf16.h>

// Problem constants
#define BATCH 2
#define SEQ 512
#define DIM 768
#define HEADS 12
#define NEXP 8
#define FFDIM 3072
#define HDIM 64
#define NTOK (BATCH*SEQ)          // 1024
#define NENT (2*NTOK)             // 2048 (token, slot) entries
#define YPS ((long)NENT * DIM)    // partial-buffer stride

typedef __hip_bfloat16 bf16;
typedef __attribute__((ext_vector_type(8))) short s8v;
typedef __attribute__((ext_vector_type(4))) float f4v;

// ---- async global->LDS (16B per lane, wave-uniform LDS base + lane*16) ----
typedef __attribute__((address_space(1))) const unsigned char gas_u8;
typedef __attribute__((address_space(3))) unsigned char las_u8;
__device__ __forceinline__ void gload16(const void* g, void* l) {
    __builtin_amdgcn_global_load_lds((gas_u8*)g, (las_u8*)l, 16, 0, 0);
}

__device__ __forceinline__ float bfbits2f(unsigned hi16) {
    union { unsigned u; float f; } c; c.u = hi16; return c.f;
}

// ---------------- LayerNorm (LN1): one block per token ----------------
__global__ __launch_bounds__(256) void ln_kernel(const float* __restrict__ x,
                                                 const float* __restrict__ g,
                                                 const float* __restrict__ b,
                                                 bf16* __restrict__ outb) {
    int t = blockIdx.x;
    const float* xr = x + (long)t * DIM;
    int tid = threadIdx.x;
    float v0 = xr[tid], v1 = xr[tid + 256], v2 = xr[tid + 512];
    float s = v0 + v1 + v2;
    __shared__ float red[4];
    #pragma unroll
    for (int o = 32; o; o >>= 1) s += __shfl_xor(s, o);
    if ((tid & 63) == 0) red[tid >> 6] = s;
    __syncthreads();
    s = red[0] + red[1] + red[2] + red[3];
    float mu = s * (1.f / DIM);
    float d0 = v0 - mu, d1 = v1 - mu, d2 = v2 - mu;
    float q = d0*d0 + d1*d1 + d2*d2;
    __shared__ float red2[4];
    #pragma unroll
    for (int o = 32; o; o >>= 1) q += __shfl_xor(q, o);
    if ((tid & 63) == 0) red2[tid >> 6] = q;
    __syncthreads();
    q = red2[0] + red2[1] + red2[2] + red2[3];
    float rstd = rsqrtf(q * (1.f / DIM) + 1e-5f);
    bf16* ob = outb + (long)t * DIM;
    ob[tid]       = __float2bfloat16(d0 * rstd * g[tid]       + b[tid]);
    ob[tid + 256] = __float2bfloat16(d1 * rstd * g[tid + 256] + b[tid + 256]);
    ob[tid + 512] = __float2bfloat16(d2 * rstd * g[tid + 512] + b[tid + 512]);
}

// ---------------- LN2 fused with x1 assembly ----------------
// x1 = x + out_b + opart0 + opart1 ; t2/t2b = LN(x1)
__global__ __launch_bounds__(256) void ln2x1_kernel(const float* __restrict__ x,
                                                    const float* __restrict__ out_b,
                                                    const float* __restrict__ op,
                                                    const float* __restrict__ g,
                                                    const float* __restrict__ b,
                                                    float* __restrict__ x1,
                                                    float* __restrict__ t2,
                                                    bf16* __restrict__ t2b) {
    int t = blockIdx.x;
    long base = (long)t * DIM;
    int tid = threadIdx.x;
    const long TDl = (long)NTOK * DIM;
    float v[3];
    #pragma unroll
    for (int i = 0; i < 3; ++i) {
        long idx = base + tid + i * 256;
        v[i] = x[idx] + out_b[tid + i * 256] + op[idx] + op[idx + TDl];
        x1[idx] = v[i];
    }
    float s = v[0] + v[1] + v[2];
    __shared__ float red[4];
    #pragma unroll
    for (int o = 32; o; o >>= 1) s += __shfl_xor(s, o);
    if ((tid & 63) == 0) red[tid >> 6] = s;
    __syncthreads();
    s = red[0] + red[1] + red[2] + red[3];
    float mu = s * (1.f / DIM);
    float d[3];
    float q = 0.f;
    #pragma unroll
    for (int i = 0; i < 3; ++i) { d[i] = v[i] - mu; q += d[i] * d[i]; }
    __shared__ float red2[4];
    #pragma unroll
    for (int o = 32; o; o >>= 1) q += __shfl_xor(q, o);
    if ((tid & 63) == 0) red2[tid >> 6] = q;
    __syncthreads();
    q = red2[0] + red2[1] + red2[2] + red2[3];
    float rstd = rsqrtf(q * (1.f / DIM) + 1e-5f);
    #pragma unroll
    for (int i = 0; i < 3; ++i) {
        long idx = base + tid + i * 256;
        float o = d[i] * rstd * g[tid + i * 256] + b[tid + i * 256];
        t2[idx] = o;
        t2b[idx] = __float2bfloat16(o);
    }
}

// ---------------- MFMA GEMM, parameterized tile (attention-side) ----------------
// C[m,n] = alpha * sum_k A[m,k] * B[n,k]   (A,B bf16 row-major [.][K])
// Tile BM=32*WM x BN=32*WN, 4 waves in 2x2 grid. LDS staged with the
// moe_gemm XOR swizzle ((row>>1)&3 on 16B k-chunks) -> conflict-free ds_read.
// OUTMODE: 0 = f32 store, 1 = bf16 store, 2 = f32 atomicAdd.
template<int WM, int WN, bool GROUPED, bool GELU, int OUTMODE>
__global__ __launch_bounds__(256) void mfma_gemm(
    const bf16* __restrict__ A, const bf16* __restrict__ B,
    const float* __restrict__ bias, const float* __restrict__ resid,
    void* __restrict__ Cv,
    int M, int N, int K, int lda, int ldb, int ldc,
    int zdiv, int ksplit,
    long a_hi, long a_lo, long b_hi, long b_lo, long c_hi, long c_lo,
    long bias_stride, const int* __restrict__ grp_off, float alpha)
{
    constexpr int BM = 32 * WM, BN = 32 * WN;
    constexpr int ACH = BM * 4;     // 16B chunks in A tile
    constexpr int BCH = BN * 4;

    int z = blockIdx.z;
    int ze = z / ksplit, ks = z % ksplit;
    int kper = K / ksplit;
    long aoff, boff, coff;
    int m_count = M;
    if (GROUPED) {
        int m0 = grp_off[ze], m1 = grp_off[ze + 1];
        m_count = m1 - m0;
        if ((int)blockIdx.y * BM >= m_count) return;
        aoff = (long)m0 * lda;
        coff = (long)m0 * ldc;
        boff = (long)ze * b_hi;
    } else {
        int zh = ze / zdiv, zl = ze % zdiv;
        aoff = zh * a_hi + zl * a_lo;
        boff = zh * b_hi + zl * b_lo;
        coff = zh * c_hi + zl * c_lo;
    }
    const short* Ag = (const short*)(A + aoff);
    const short* Bg = (const short*)(B + boff);
    const float* biasp = bias ? bias + (long)ze * bias_stride : nullptr;
    float* Cf = (float*)Cv + coff;
    bf16*  Cb = (bf16*)Cv + coff;

    __shared__ short As[BM * 32];
    __shared__ short Bs[BN * 32];

    int tid = threadIdx.x;
    int wv = tid >> 6, ln = tid & 63;
    int wr = wv >> 1, wc = wv & 1;
    int fr = ln & 15, fq = ln >> 4;
    int bm = blockIdx.y * BM, bn = blockIdx.x * BN;

    f4v acc[WM][WN] = {};

    for (int k0 = ks * kper; k0 < (ks + 1) * kper; k0 += 32) {
        #pragma unroll
        for (int is = 0; is < ACH / 256; ++is) {
            int c = is * 256 + wv * 64 + ln;
            int m = c >> 2, kq = c & 3;
            int qg = kq ^ ((m >> 1) & 3);
            gload16(Ag + (long)(bm + m) * lda + k0 + qg * 8,
                    &As[(is * 256 + wv * 64) * 8]);
        }
        if constexpr (ACH % 256) {
            if (tid < ACH % 256) {
                int c = (ACH / 256) * 256 + tid;
                int m = c >> 2, kq = c & 3;
                int qg = kq ^ ((m >> 1) & 3);
                gload16(Ag + (long)(bm + m) * lda + k0 + qg * 8,
                        &As[((ACH / 256) * 256 + wv * 64) * 8]);
            }
        }
        #pragma unroll
        for (int is = 0; is < BCH / 256; ++is) {
            int c = is * 256 + wv * 64 + ln;
            int m = c >> 2, kq = c & 3;
            int qg = kq ^ ((m >> 1) & 3);
            gload16(Bg + (long)(bn + m) * ldb + k0 + qg * 8,
                    &Bs[(is * 256 + wv * 64) * 8]);
        }
        if constexpr (BCH % 256) {
            if (tid < BCH % 256) {
                int c = (BCH / 256) * 256 + tid;
                int m = c >> 2, kq = c & 3;
                int qg = kq ^ ((m >> 1) & 3);
                gload16(Bg + (long)(bn + m) * ldb + k0 + qg * 8,
                        &Bs[((BCH / 256) * 256 + wv * 64) * 8]);
            }
        }
        __syncthreads();
        s8v av[WM], bv[WN];
        #pragma unroll
        for (int i = 0; i < WM; ++i) {
            int row = wr * (WM * 16) + i * 16 + fr;
            av[i] = *(const s8v*)&As[row * 32 + (fq ^ ((row >> 1) & 3)) * 8];
        }
        #pragma unroll
        for (int j = 0; j < WN; ++j) {
            int row = wc * (WN * 16) + j * 16 + fr;
            bv[j] = *(const s8v*)&Bs[row * 32 + (fq ^ ((row >> 1) & 3)) * 8];
        }
        #pragma unroll
        for (int i = 0; i < WM; ++i)
            #pragma unroll
            for (int j = 0; j < WN; ++j)
                acc[i][j] = __builtin_amdgcn_mfma_f32_16x16x32_bf16(av[i], bv[j], acc[i][j], 0, 0, 0);
        __syncthreads();
    }

    #pragma unroll
    for (int i = 0; i < WM; ++i) {
        #pragma unroll
        for (int r = 0; r < 4; ++r) {
            int row = bm + wr * (WM * 16) + i * 16 + fq * 4 + r;
            if (GROUPED && row >= m_count) continue;
            #pragma unroll
            for (int j = 0; j < WN; ++j) {
                int col = bn + wc * (WN * 16) + j * 16 + fr;
                if (col < N) {
                    float v = acc[i][j][r] * alpha;
                    if (OUTMODE == 2) {
                        atomicAdd(&Cf[(long)row * ldc + col], v);
                    } else {
                        if (biasp) v += biasp[col];
                        if (GELU) v = 0.5f * v * (1.f + erff(v * 0.70710678118654752f));
                        if (resid) v += resid[(long)row * ldc + col];
                        if (OUTMODE == 1) Cb[(long)row * ldc + col] = __float2bfloat16(v);
                        else              Cf[(long)row * ldc + col] = v;
                    }
                }
            }
        }
    }
}

// ---------------- MoE grouped GEMM v11: gather-fused A, split-K partial stores
// BM=FM*32, BN=FN*32 (2x2 wave grid), BK=32, 3 LDS buffers, counted vmcnt(G).
// GATHER: A row for block-row m is entry_tok[m0+bm+m] (indices preloaded into
// registers — fixed per (thread, chunk)); else A rows contiguous from m0.
// B bf16 [e][N][ldb]; staged via gload_lds with global-side XOR swizzle.
// OUTMODE: 0 = f32 store at ks*pstride (split-K partials); 1 = bf16 store
// (+bias,+GELU) — requires KS==1.
template<int FM, int FN, int XT, int YCAP, int KS, bool GELU, int OUTMODE, bool GATHER>
__global__ __launch_bounds__(256) void moe_gemm(
    const bf16* __restrict__ A, const bf16* __restrict__ B,
    const float* __restrict__ bias, void* __restrict__ Cv,
    int lda, int ldb, int ldc, int Ktot, long b_hi, long bias_stride,
    const int* __restrict__ grp_off, const int* __restrict__ entry_tok,
    int N, long pstride)
{
    static_assert(OUTMODE != 1 || KS == 1, "plain bf16 store requires no split-K");
    constexpr int BM = FM * 32, BN = FN * 32;
    constexpr int GA = BM / 64;          // A gload16 per wave per tile
    constexpr int GB = BN / 64;          // B gload16 per wave per tile
    constexpr int G = GA + GB;

    int bid = blockIdx.x;
    int e = bid & 7;
    int r = bid >> 3;
    int xt = r % XT; r /= XT;
    int yt = r % YCAP;
    int ks = r / YCAP;
    int m0 = grp_off[e], m1 = grp_off[e + 1];
    int m_count = m1 - m0;
    int bm = yt * BM;
    if (bm >= m_count) return;
    int bn = xt * BN;
    int kper = Ktot / KS;                // multiple of 32

    const short* Ag = (const short*)A + (GATHER ? 0 : (long)m0 * lda);
    const short* Bg = (const short*)(B + (long)e * b_hi);
    const float* biasp = bias ? bias + (long)e * bias_stride : nullptr;
    float* Cf = (float*)Cv + (long)m0 * ldc + (long)ks * pstride;
    bf16*  Cb = (bf16*)Cv + (long)m0 * ldc;

    __shared__ short As[3][BM * 32];     // [m][k] rows of 64B
    __shared__ short Bs[3][BN * 32];     // [n][k]

    int tid = threadIdx.x;
    int wv = tid >> 6, ln = tid & 63;
    int wr = wv >> 1, wc = wv & 1;       // 2x2 wave grid
    int fr = ln & 15, fq = ln >> 4;      // fq in 0..3 = 16B k-chunk

    // Per-thread A row bases (fixed across K iterations).
    long arow[GA];
    #pragma unroll
    for (int is = 0; is < GA; ++is) {
        int c = is * 256 + wv * 64 + ln;
        int m = c >> 2;
        if (GATHER) {
            int gi = m0 + bm + m;
            arow[is] = (long)entry_tok[gi < NENT ? gi : NENT - 1] * lda;
        } else {
            arow[is] = (long)(bm + m) * lda;
        }
    }

    f4v acc[FM][FN] = {};

    auto stage = [&](int buf, int k0) {
        #pragma unroll
        for (int is = 0; is < GA; ++is) {
            int c = is * 256 + wv * 64 + ln;       // A chunks
            int m = c >> 2, q = c & 3;
            int qg = q ^ ((m >> 1) & 3);
            gload16(Ag + arow[is] + k0 + qg * 8,
                    &As[buf][(is * 256 + wv * 64) * 8]);
        }
        #pragma unroll
        for (int is = 0; is < GB; ++is) {
            int c = is * 256 + wv * 64 + ln;       // B chunks
            int n = c >> 2, q = c & 3;
            int qg = q ^ ((n >> 1) & 3);
            gload16(Bg + (long)(bn + n) * ldb + k0 + qg * 8,
                    &Bs[buf][(is * 256 + wv * 64) * 8]);
        }
    };

    int kbeg = ks * kper;
    int nit = kper / 32;
    stage(0, kbeg);
    if (nit > 1) stage(1, kbeg + 32);

    for (int it = 0; it < nit; ++it) {
        if (it + 1 < nit) asm volatile("s_waitcnt vmcnt(%0)" :: "i"(G) : "memory");
        else              asm volatile("s_waitcnt vmcnt(0)" ::: "memory");
        __builtin_amdgcn_s_barrier();
        if (it + 2 < nit) stage((it + 2) % 3, kbeg + (it + 2) * 32);
        int cur = it % 3;
        __builtin_amdgcn_s_setprio(1);
        {
            s8v av[FM], bv[FN];
            #pragma unroll
            for (int i = 0; i < FM; ++i) {
                int row = wr * (FM * 16) + i * 16 + fr;
                av[i] = *(const s8v*)&As[cur][row * 32 + (fq ^ ((row >> 1) & 3)) * 8];
            }
            #pragma unroll
            for (int j = 0; j < FN; ++j) {
                int row = wc * (FN * 16) + j * 16 + fr;
                bv[j] = *(const s8v*)&Bs[cur][row * 32 + (fq ^ ((row >> 1) & 3)) * 8];
            }
            #pragma unroll
            for (int i = 0; i < FM; ++i)
                #pragma unroll
                for (int j = 0; j < FN; ++j)
                    acc[i][j] = __builtin_amdgcn_mfma_f32_16x16x32_bf16(av[i], bv[j], acc[i][j], 0, 0, 0);
        }
        __builtin_amdgcn_s_setprio(0);
    }

    #pragma unroll
    for (int i = 0; i < FM; ++i) {
        #pragma unroll
        for (int rr = 0; rr < 4; ++rr) {
            int row = bm + wr * (FM * 16) + i * 16 + fq * 4 + rr;
            if (row >= m_count) continue;
            #pragma unroll
            for (int j = 0; j < FN; ++j) {
                int col = bn + wc * (FN * 16) + j * 16 + fr;
                float v = acc[i][j][rr];
                if (OUTMODE == 0) {
                    Cf[(long)row * ldc + col] = v;          // split-K partial
                } else {
                    if (biasp) v += biasp[col];
                    if (GELU) v = 0.5f * v * (1.f + erff(v * 0.70710678118654752f));
                    Cb[(long)row * ldc + col] = __float2bfloat16(v);
                }
            }
        }
    }
}

// ---------------- softmax over 512, bf16 in -> bf16 out, wave per row --------
__global__ __launch_bounds__(256) void softmax512b(const bf16* __restrict__ s,
                                                   bf16* __restrict__ attn) {
    long row = (long)blockIdx.x * 4 + (threadIdx.x >> 6);
    int ln = threadIdx.x & 63;
    const unsigned* p = (const unsigned*)(s + row * 512);
    uint4 v = *(const uint4*)(p + ln * 4);
    unsigned u[4] = {v.x, v.y, v.z, v.w};
    float f[8];
    #pragma unroll
    for (int j = 0; j < 4; ++j) {
        f[2*j]   = bfbits2f(u[j] << 16);
        f[2*j+1] = bfbits2f(u[j] & 0xffff0000u);
    }
    float m = f[0];
    #pragma unroll
    for (int j = 1; j < 8; ++j) m = fmaxf(m, f[j]);
    #pragma unroll
    for (int o = 32; o; o >>= 1) m = fmaxf(m, __shfl_xor(m, o));
    float e[8], ssum = 0.f;
    #pragma unroll
    for (int j = 0; j < 8; ++j) { e[j] = expf(f[j] - m); ssum += e[j]; }
    #pragma unroll
    for (int o = 32; o; o >>= 1) ssum += __shfl_xor(ssum, o);
    float inv = 1.f / ssum;
    unsigned w[4];
    #pragma unroll
    for (int j = 0; j < 4; ++j) {
        bf16 lo = __float2bfloat16(e[2*j] * inv);
        bf16 hi = __float2bfloat16(e[2*j+1] * inv);
        w[j] = ((unsigned)*(unsigned short*)&hi << 16) | *(unsigned short*)&lo;
    }
    uint4 o4; o4.x = w[0]; o4.y = w[1]; o4.z = w[2]; o4.w = w[3];
    *(uint4*)((unsigned*)(attn + row * 512) + ln * 4) = o4;
}

// ---------------- V transpose: qkv bf16 [tok][2304] -> vt [z][64][512] ------
__global__ __launch_bounds__(256) void vt_kernel(const bf16* __restrict__ qkvb,
                                                 bf16* __restrict__ vt) {
    int st = blockIdx.x;
    int z = blockIdx.y;
    int b = z / HEADS, h = z % HEADS;
    __shared__ short tile[64][65];
    int t = threadIdx.x;
    int d = t & 63, s0 = t >> 6;
    const short* q = (const short*)qkvb;
    #pragma unroll
    for (int i = 0; i < 16; ++i) {
        int s = st * 64 + s0 + i * 4;
        tile[s0 + i * 4][d] = q[(long)(b * SEQ + s) * 2304 + 2 * DIM + h * HDIM + d];
    }
    __syncthreads();
    short* o = (short*)vt;
    #pragma unroll
    for (int i = 0; i < 16; ++i) {
        int d2 = (t >> 6) + i * 4;
        o[(long)(z * 64 + d2) * 512 + st * 64 + (t & 63)] = tile[t & 63][d2];
    }
}

// ---------------- merged weight transpose-convert (w1 + w2) ----------------
// (r16 proven version: scalar but fully coalesced loads AND stores, 0 conflicts)
__global__ __launch_bounds__(256) void wtrans2_kernel(const float* __restrict__ w1,
                                                      bf16* __restrict__ w1t,
                                                      const float* __restrict__ w2,
                                                      bf16* __restrict__ w2t) {
    int id = blockIdx.x;                 // 0..9215
    const float* in; bf16* out; int R, C, e, ct, rt;
    if (id < 4608) {                     // w1: 8 x (48 ct x 12 rt)
        e = id / 576; int rem = id % 576; ct = rem / 12; rt = rem % 12;
        in = w1; out = w1t; R = DIM; C = FFDIM;
    } else {                             // w2: 8 x (12 ct x 48 rt)
        id -= 4608;
        e = id / 576; int rem = id % 576; ct = rem / 48; rt = rem % 48;
        in = w2; out = w2t; R = FFDIM; C = DIM;
    }
    long ibase = (long)e * R * C;
    int rt0 = rt * 64, ct0 = ct * 64;
    __shared__ float tile[64][65];
    int t = threadIdx.x;
    int c = t & 63, r0 = t >> 6;
    #pragma unroll
    for (int i = 0; i < 16; ++i)
        tile[r0 + i * 4][c] = in[ibase + (long)(rt0 + r0 + i * 4) * C + ct0 + c];
    __syncthreads();
    #pragma unroll
    for (int i = 0; i < 16; ++i) {
        int cc = r0 + i * 4;
        out[ibase + (long)(ct0 + cc) * R + rt0 + c] = __float2bfloat16(tile[c][cc]);
    }
}

// ---------------- dual f32 -> bf16 convert (merged launches) ----------------
__global__ __launch_bounds__(256) void cvt2_kernel(const float* __restrict__ a, long na,
                                                   const float* __restrict__ b, long nb,
                                                   bf16* __restrict__ oa,
                                                   bf16* __restrict__ ob) {
    long i = ((long)blockIdx.x * 256 + threadIdx.x) * 4;
    const float* src; bf16* dst; long idx;
    if (i < na) { src = a; dst = oa; idx = i; }
    else if (i < na + nb) { src = b; dst = ob; idx = i - na; }
    else return;
    float4 v = *(const float4*)(src + idx);
    dst[idx]     = __float2bfloat16(v.x);
    dst[idx + 1] = __float2bfloat16(v.y);
    dst[idx + 2] = __float2bfloat16(v.z);
    dst[idx + 3] = __float2bfloat16(v.w);
}

// ---------------- router: logits, softmax, top2, renorm ----------------
__global__ __launch_bounds__(64) void router_kernel(const float* __restrict__ t2,
                                                    const float* __restrict__ rw,
                                                    const float* __restrict__ rb,
                                                    int* __restrict__ e_sel,
                                                    float* __restrict__ w_sel) {
    int t = blockIdx.x;
    int lane = threadIdx.x;
    const float* tr = t2 + (long)t * DIM;
    float tv[12];
    #pragma unroll
    for (int i = 0; i < 12; ++i) tv[i] = tr[lane + 64 * i];
    float logits[NEXP];
    #pragma unroll
    for (int e = 0; e < NEXP; ++e) {
        const float* wr = rw + (long)e * DIM;
        float s = 0.f;
        #pragma unroll
        for (int i = 0; i < 12; ++i) s += tv[i] * wr[lane + 64 * i];
        #pragma unroll
        for (int o = 32; o; o >>= 1) s += __shfl_xor(s, o);
        logits[e] = s + rb[e];
    }
    if (lane == 0) {
        int e0 = -1, e1 = -1;
        float l0 = -1e30f, l1 = -1e30f;
        #pragma unroll
        for (int e = 0; e < NEXP; ++e) {
            float l = logits[e];
            if (l > l0) { l1 = l0; e1 = e0; l0 = l; e0 = e; }
            else if (l > l1) { l1 = l; e1 = e; }
        }
        float p1 = expf(l1 - l0);
        float inv = 1.f / (1.f + p1);
        e_sel[t * 2] = e0;  e_sel[t * 2 + 1] = e1;
        w_sel[t * 2] = inv; w_sel[t * 2 + 1] = p1 * inv;
    }
}

// ---------------- build per-expert entry lists (single block) ----------------
__global__ __launch_bounds__(1024) void build_lists(const int* __restrict__ e_sel,
                                                    int* __restrict__ entry_tok,
                                                    int* __restrict__ pos,
                                                    int* __restrict__ grp_off) {
    __shared__ int cnt[NEXP];
    __shared__ int off[NEXP + 1];
    __shared__ int cur[NEXP];
    int tid = threadIdx.x;
    if (tid < NEXP) cnt[tid] = 0;
    __syncthreads();
    for (int i = tid; i < NENT; i += 1024) atomicAdd(&cnt[e_sel[i]], 1);
    __syncthreads();
    if (tid == 0) {
        off[0] = 0;
        for (int e = 0; e < NEXP; ++e) off[e + 1] = off[e] + cnt[e];
        for (int e = 0; e < NEXP; ++e) cur[e] = off[e];
    }
    __syncthreads();
    for (int i = tid; i < NENT; i += 1024) {
        int e = e_sel[i];
        int p = atomicAdd(&cur[e], 1);
        entry_tok[p] = i >> 1;
        pos[i] = p;
    }
    if (tid < NEXP + 1) grp_off[tid] = off[tid];
}

// ---------------- final combine (float4): out = x1 + sum_s w_s*(b2+sum parts) -
__global__ __launch_bounds__(256) void combine_kernel(const float* __restrict__ x1,
                                                      const float* __restrict__ ypart,
                                                      const float* __restrict__ b2,
                                                      const int* __restrict__ pos,
                                                      const int* __restrict__ e_sel,
                                                      const float* __restrict__ wsel,
                                                      float* __restrict__ out) {
    long i4 = (long)blockIdx.x * 256 + threadIdx.x;      // float4 units; 196608 total
    if (i4 >= (long)NTOK * DIM / 4) return;
    int t = (int)(i4 / 192), d4 = (int)(i4 % 192);
    const float4* x1v = (const float4*)x1;
    const float4* ypv = (const float4*)ypart;
    const float4* b2v = (const float4*)b2;
    float4 v = x1v[i4];
    #pragma unroll
    for (int s = 0; s < 2; ++s) {
        long base = (long)pos[t * 2 + s] * 192 + d4;
        float4 y = b2v[(long)e_sel[t * 2 + s] * 192 + d4];
        #pragma unroll
        for (int ks = 0; ks < 4; ++ks) {
            float4 pp = ypv[base + ks * (YPS / 4)];
            y.x += pp.x; y.y += pp.y; y.z += pp.z; y.w += pp.w;
        }
        float w = wsel[t * 2 + s];
        v.x += w * y.x; v.y += w * y.y; v.z += w * y.z; v.w += w * y.w;
    }
    ((float4*)out)[i4] = v;
}

extern "C" void kernel_launch(void* const* d_in, const int* in_sizes, int n_in,
                              void* d_out, int out_size, void* d_ws, size_t ws_size,
                              hipStream_t stream) {
    const float* x        = (const float*)d_in[0];
    const float* ln1_g    = (const float*)d_in[1];
    const float* ln1_b    = (const float*)d_in[2];
    const float* ln2_g    = (const float*)d_in[3];
    const float* ln2_b    = (const float*)d_in[4];
    const float* in_w     = (const float*)d_in[5];
    const float* in_b     = (const float*)d_in[6];
    const float* out_w    = (const float*)d_in[7];
    const float* out_b    = (const float*)d_in[8];
    const float* router_w = (const float*)d_in[9];
    const float* router_b = (const float*)d_in[10];
    const float* w1       = (const float*)d_in[11];
    const float* b1       = (const float*)d_in[12];
    const float* w2       = (const float*)d_in[13];
    const float* b2       = (const float*)d_in[14];
    float* out = (float*)d_out;

    const long TD = (long)NTOK * DIM;
    char* p = (char*)d_ws;
    size_t off = 0;
    auto alloc = [&](size_t bytes) -> void* {
        void* r = p + off; off += (bytes + 255) & ~(size_t)255; return r;
    };
    bf16*  h_b    = (bf16*)alloc(TD * 2);
    bf16*  in_wb  = (bf16*)alloc(2304L * 768 * 2);
    bf16*  qkv_b  = (bf16*)alloc(1024L * 2304 * 2);
    bf16*  out_wb = (bf16*)alloc(768L * 768 * 2);
    bf16*  vt_b   = (bf16*)alloc((24L * 64 + 64) * 512 * 2);
    bf16*  oat_b  = (bf16*)alloc(TD * 2);
    float* opart  = (float*)alloc(2 * TD * 4);                 // out-proj K-partials
    float* x1     = (float*)alloc(TD * 4);
    float* t2     = (float*)alloc(TD * 4);
    bf16*  t2b    = (bf16*)alloc((NTOK + 256L) * DIM * 2);     // +pad (BM overread)
    bf16*  w1t    = (bf16*)alloc(8L * 3072 * 768 * 2);         // aliased: scores+attn bf16
    bf16*  w2t    = (bf16*)alloc(8L * 768 * 3072 * 2);
    bf16*  hid    = (bf16*)alloc((2048L + 256) * 3072 * 2);    // +pad
    float* ypart  = (float*)alloc(4 * YPS * 4);                // 4 split-K partials
    int*   e_sel     = (int*)alloc(NENT * 4);
    float* w_sel     = (float*)alloc(NENT * 4);
    int*   entry_tok = (int*)alloc(NENT * 4);
    int*   pos       = (int*)alloc(NENT * 4);
    int*   grp_off   = (int*)alloc(64);
    // scores/attn (bf16, 12.58 MB each) alias the not-yet-written w1t region;
    // wtrans2 runs only after PV has consumed attn.
    bf16* scores = w1t;
    bf16* attn   = (bf16*)((char*)w1t + 24L * 512 * 512 * 2);

    // 1. LN1 -> h bf16
    ln_kernel<<<NTOK, 256, 0, stream>>>(x, ln1_g, ln1_b, h_b);
    // 2. attention weight converts (merged; already [N][K])
    cvt2_kernel<<<2304, 256, 0, stream>>>(in_w, 2304L * 768, out_w, 768L * 768,
                                          in_wb, out_wb);
    // 3. qkv = h @ in_w^T + in_b -> bf16 [1024,2304]   BN=64: 576 blocks
    mfma_gemm<2, 2, false, false, 1><<<dim3(36, 16, 1), 256, 0, stream>>>(
        h_b, in_wb, in_b, nullptr, qkv_b,
        NTOK, 3 * DIM, DIM, DIM, DIM, 3 * DIM,
        1, 1, 0, 0, 0, 0, 0, 0, 0, nullptr, 1.f);
    // 4. scores = Q @ K^T / 8 -> bf16 [24][512][512]   768 blocks
    mfma_gemm<2, 4, false, false, 1><<<dim3(4, 8, 24), 256, 0, stream>>>(
        qkv_b, qkv_b + DIM, nullptr, nullptr, scores,
        SEQ, SEQ, HDIM, 3 * DIM, 3 * DIM, SEQ,
        HEADS, 1, (long)SEQ * 3 * DIM, HDIM, (long)SEQ * 3 * DIM, HDIM,
        (long)HEADS * SEQ * SEQ, (long)SEQ * SEQ,
        0, nullptr, 0.125f);
    // 5. softmax (wave per row) -> attn bf16
    softmax512b<<<24 * SEQ / 4, 256, 0, stream>>>(scores, attn);
    // 6. V transpose
    vt_kernel<<<dim3(8, 24), 256, 0, stream>>>(qkv_b, vt_b);
    // 7. o = attn @ V -> oat bf16   BM=32: 384 blocks
    mfma_gemm<1, 2, false, false, 1><<<dim3(1, 16, 24), 256, 0, stream>>>(
        attn, vt_b, nullptr, nullptr, oat_b,
        SEQ, HDIM, SEQ, SEQ, SEQ, DIM,
        HEADS, 1, (long)HEADS * SEQ * SEQ, (long)SEQ * SEQ,
        (long)HEADS * HDIM * SEQ, (long)HDIM * SEQ,
        (long)SEQ * DIM, HDIM,
        0, nullptr, 1.f);
    // 8. out-proj split-K x2, plain partial stores (no atomics, no prefill):
    //    opart[z] = oat[:, z*384:] @ out_w[:, z*384:]^T
    mfma_gemm<2, 2, false, false, 0><<<dim3(12, 16, 2), 256, 0, stream>>>(
        oat_b, out_wb, nullptr, nullptr, opart,
        NTOK, DIM, 384, DIM, DIM, DIM,
        2, 1, 0, 384, 0, 384, 0, TD, 0, nullptr, 1.f);
    // 9. LN2 fused with x1 assembly: x1 = x + out_b + opart0 + opart1; LN -> t2,t2b
    ln2x1_kernel<<<NTOK, 256, 0, stream>>>(x, out_b, opart, ln2_g, ln2_b,
                                           x1, t2, t2b);
    // 10. router
    router_kernel<<<NTOK, 64, 0, stream>>>(t2, router_w, router_b, e_sel, w_sel);
    // 11. build lists
    build_lists<<<1, 1024, 0, stream>>>(e_sel, entry_tok, pos, grp_off);
    // 12. merged weight transpose-convert (r16 proven scalar-coalesced version)
    wtrans2_kernel<<<9216, 256, 0, stream>>>(w1, w1t, w2, w2t);
    // 13. FFN1 grouped, GATHER-fused A: hid = gelu(t2b[tok] @ w1t^T + b1) -> bf16
    moe_gemm<4, 4, 24, 8, 1, true, 1, true><<<8 * 24 * 8, 256, 0, stream>>>(
        t2b, w1t, b1, hid,
        DIM, DIM, FFDIM, DIM, (long)FFDIM * DIM, FFDIM, grp_off, entry_tok,
        FFDIM, 0);
    // 14. FFN2 grouped split-K x4, plain partial stores
    moe_gemm<4, 4, 6, 8, 4, false, 0, false><<<8 * 6 * 8 * 4, 256, 0, stream>>>(
        hid, w2t, nullptr, ypart,
        FFDIM, FFDIM, DIM, FFDIM, (long)DIM * FFDIM, 0, grp_off, nullptr,
        DIM, YPS);
    // 15. combine (float4): out = x1 + sum_s w_s*(b2[e_s] + sum_ks ypart)
    combine_kernel<<<768, 256, 0, stream>>>(x1, ypart, b2, pos, e_sel, w_sel, out);
}